// Round 2
// baseline (147.323 us; speedup 1.0000x reference)
//
#include <hip/hip_runtime.h>
#include <math.h>

#define HDIM 128

// ---------------------------------------------------------------------------
// Fused bounds + init + out-zero. segment_ids is sorted; starts[s] = first t
// with seg[t] >= s. Thread t covers (seg[t-1], seg[t]]; thread 0 covers
// [0, seg[0]]; thread T-1 covers trailing empty segments (seg[T-1], B] with T.
// These three cases tile [0, B] exactly, so no init pass is needed.
// ---------------------------------------------------------------------------
__global__ void seg_bounds_kernel(const int* __restrict__ seg,
                                  int* __restrict__ starts, int Tval, int Bval,
                                  float* __restrict__ out) {
    int t = blockIdx.x * blockDim.x + threadIdx.x;
    if (t >= Tval) return;
    int b = seg[t];
    int a = (t == 0) ? -1 : seg[t - 1];
    for (int s = a + 1; s <= b; ++s) starts[s] = t;
    if (t == Tval - 1)
        for (int s = b + 1; s <= Bval; ++s) starts[s] = Tval;
    if (t == 0) out[0] = 0.0f;
}

// ---------------------------------------------------------------------------
// Fused gather-mean + MLP head + BCE. TWO waves per segment (grid = B/2
// blocks x 4 waves => 8192 waves = 100% of wave slots; R1 had 50% max).
// Gather: wave sub (0/1), half-wave h: tokens t0 + 2*sub + h, stride 4;
// float4/lane => 512 B row per half-wave per instr, 8 rows in flight.
// Matvec is linear, so each wave computes a PARTIAL matvec on its own
// partial token sum (no wave idles while streaming the 64 KB W from L2);
// partials combined cross-wave via one float2/lane LDS exchange, then
// bias + tanh + Wo-dot (shfl_xor reduce) + BCE on lane 0, one atomic/block.
// ---------------------------------------------------------------------------
__global__ __launch_bounds__(256) void fused_dan_kernel(
    const int* __restrict__ tok, const float* __restrict__ emb,
    const int* __restrict__ starts, const float* __restrict__ Wh,
    const float* __restrict__ bh, const float* __restrict__ Wo,
    const float* __restrict__ bo, const float* __restrict__ y,
    float* __restrict__ out, int Bval) {
    __shared__ float slds[4][HDIM];     // per-wave partial token-sum strip
    __shared__ float2 pmat[4][64];      // per-wave partial matvec results
    __shared__ float lred[4];

    int wave = threadIdx.x >> 6;
    int lane = threadIdx.x & 63;
    int sub  = wave & 1;                // which wave of the segment pair
    int s    = blockIdx.x * 2 + (wave >> 1);
    float lsum = 0.0f;

    float a0 = 0.0f, a1 = 0.0f;         // partial matvec accumulators
    float inv = 0.0f;

    if (s < Bval) {
        int t0 = starts[s];
        int t1 = starts[s + 1];
        int cnt = t1 - t0;
        inv = 1.0f / (float)(cnt > 0 ? cnt : 1);

        int half = lane >> 5;           // token slot within this wave
        int col  = lane & 31;           // float4 column within the 128-f row

        float4 acc = make_float4(0.f, 0.f, 0.f, 0.f);
        int i = t0 + 2 * sub + half;    // this half-wave's stream, stride 4

        // main loop: 8 tokens per half-wave per iter, 8 gathers in flight
        for (; i + 28 < t1; i += 32) {
            int tix[8];
            #pragma unroll
            for (int k = 0; k < 8; ++k) tix[k] = tok[i + 4 * k];
            float4 f[8];
            #pragma unroll
            for (int k = 0; k < 8; ++k)
                f[k] = ((const float4*)(emb + (size_t)tix[k] * HDIM))[col];
            #pragma unroll
            for (int k = 0; k < 8; ++k) {
                acc.x += f[k].x; acc.y += f[k].y;
                acc.z += f[k].z; acc.w += f[k].w;
            }
        }
        // masked epilogue: one clamped 8-deep iteration covers the tail
        if (i < t1) {
            int lim = t1 - 1;
            int tix[8]; float msk[8];
            #pragma unroll
            for (int k = 0; k < 8; ++k) {
                int ii = i + 4 * k;
                tix[k] = tok[ii < lim ? ii : lim];
                msk[k] = (ii < t1) ? 1.0f : 0.0f;
            }
            float4 f[8];
            #pragma unroll
            for (int k = 0; k < 8; ++k)
                f[k] = ((const float4*)(emb + (size_t)tix[k] * HDIM))[col];
            #pragma unroll
            for (int k = 0; k < 8; ++k) {
                acc.x = fmaf(f[k].x, msk[k], acc.x);
                acc.y = fmaf(f[k].y, msk[k], acc.y);
                acc.z = fmaf(f[k].z, msk[k], acc.z);
                acc.w = fmaf(f[k].w, msk[k], acc.w);
            }
        }

        // combine the two half-wave partials (lane l += lane l+32)
        acc.x += __shfl_down(acc.x, 32);
        acc.y += __shfl_down(acc.y, 32);
        acc.z += __shfl_down(acc.z, 32);
        acc.w += __shfl_down(acc.w, 32);

        if (half == 0)
            ((float4*)&slds[wave][0])[col] = acc;   // own strip, same-wave RAW

        // partial matvec on OWN partial sum (linearity: (m0+m1)W = m0W + m1W)
        const float2* W2 = (const float2*)Wh;
        const float4* s4 = (const float4*)&slds[wave][0];
        #pragma unroll 4
        for (int q = 0; q < HDIM / 4; ++q) {
            float4 sv = s4[q];
            float2 w0 = W2[(4 * q + 0) * (HDIM / 2) + lane];
            float2 w1 = W2[(4 * q + 1) * (HDIM / 2) + lane];
            float2 w2 = W2[(4 * q + 2) * (HDIM / 2) + lane];
            float2 w3 = W2[(4 * q + 3) * (HDIM / 2) + lane];
            a0 = fmaf(sv.x, w0.x, a0); a1 = fmaf(sv.x, w0.y, a1);
            a0 = fmaf(sv.y, w1.x, a0); a1 = fmaf(sv.y, w1.y, a1);
            a0 = fmaf(sv.z, w2.x, a0); a1 = fmaf(sv.z, w2.y, a1);
            a0 = fmaf(sv.w, w3.x, a0); a1 = fmaf(sv.w, w3.y, a1);
        }
        a0 *= inv; a1 *= inv;           // token-sum -> mean (bias added later)
        pmat[wave][lane] = make_float2(a0, a1);
    }
    __syncthreads();                    // all waves reach this (uniform guard)

    if (sub == 0 && s < Bval) {
        float2 pp = pmat[wave ^ 1][lane];
        float2 bh2 = ((const float2*)bh)[lane];
        float2 wo2 = ((const float2*)Wo)[lane];
        float h0 = tanhf(a0 + pp.x + bh2.x);
        float h1 = tanhf(a1 + pp.y + bh2.y);
        float pr = h0 * wo2.x + h1 * wo2.y;
        #pragma unroll
        for (int mm = 1; mm < 64; mm <<= 1) pr += __shfl_xor(pr, mm);
        if (lane == 0) {
            float z = pr + bo[0];
            float p = 1.0f / (1.0f + expf(-z));
            float lp  = fmaxf(logf(p),    -100.0f);
            float l1p = fmaxf(log1pf(-p), -100.0f);
            float yv = y[s];
            lsum = -(yv * lp + (1.0f - yv) * l1p);
        }
    }

    if (lane == 0) lred[wave] = lsum;   // waves 1,3 contribute 0
    __syncthreads();
    if (threadIdx.x == 0)
        atomicAdd(out, lred[0] + lred[1] + lred[2] + lred[3]);
}

// ---------------------------------------------------------------------------
extern "C" void kernel_launch(void* const* d_in, const int* in_sizes, int n_in,
                              void* d_out, int out_size, void* d_ws, size_t ws_size,
                              hipStream_t stream) {
    const int*   tok = (const int*)d_in[0];
    const int*   seg = (const int*)d_in[1];
    const float* y   = (const float*)d_in[2];
    const float* emb = (const float*)d_in[3];
    const float* Wh  = (const float*)d_in[4];
    const float* bh  = (const float*)d_in[5];
    const float* Wo  = (const float*)d_in[6];
    const float* bo  = (const float*)d_in[7];

    int T_ = in_sizes[0];
    int B_ = in_sizes[2];

    float* out = (float*)d_out;
    int* starts = (int*)d_ws;   // only B+1 ints of workspace needed

    seg_bounds_kernel<<<(T_ + 255) / 256, 256, 0, stream>>>(seg, starts, T_, B_, out);
    fused_dan_kernel<<<(B_ + 1) / 2, 256, 0, stream>>>(tok, emb, starts, Wh, bh, Wo,
                                                       bo, y, out, B_);
}

// Round 3
// 131.613 us; speedup vs baseline: 1.1194x; 1.1194x over previous
//
#include <hip/hip_runtime.h>
#include <math.h>

#define HDIM 128

// ---------------------------------------------------------------------------
// Fused bounds + init + out-zero. segment_ids is sorted; starts[s] = first t
// with seg[t] >= s. Thread t covers (seg[t-1], seg[t]]; thread 0 covers
// [0, seg[0]]; thread T-1 covers trailing empty segments (seg[T-1], B] with T.
// ---------------------------------------------------------------------------
__global__ void seg_bounds_kernel(const int* __restrict__ seg,
                                  int* __restrict__ starts, int Tval, int Bval,
                                  float* __restrict__ out) {
    int t = blockIdx.x * blockDim.x + threadIdx.x;
    if (t >= Tval) return;
    int b = seg[t];
    int a = (t == 0) ? -1 : seg[t - 1];
    for (int s = a + 1; s <= b; ++s) starts[s] = t;
    if (t == Tval - 1)
        for (int s = b + 1; s <= Bval; ++s) starts[s] = Tval;
    if (t == 0) out[0] = 0.0f;
}

// ---------------------------------------------------------------------------
// Fused gather-mean + MLP head + BCE. ONE wave per segment (R1 structure —
// R2's 2-wave split regressed: it doubled per-wave fixed latency + W traffic).
// The R1/R2 kernels showed VGPR=36: the "8-deep" gather was really ~2-deep
// (compiler serialized loads to save registers). This version forces real
// depth 8:
//   - token ids software-pipelined one iteration ahead (tix/ntix), so emb
//     row loads issue without waiting on the tok fetch;
//   - sched_barrier(0) between the 8 row loads and their accumulation keeps
//     all 8 float4 results live => all 8 loads in flight per half-wave.
// MLP: mean -> 512 B LDS strip -> lane l owns hidden cols 2l,2l+1, streams
// W_hid rows from global (L2-hot), 2-way split accumulators to halve the
// serial FMA chain. tanh -> Wo dot via shfl_xor -> BCE -> one atomic/block.
// ---------------------------------------------------------------------------
__global__ __launch_bounds__(256) void fused_dan_kernel(
    const int* __restrict__ tok, const float* __restrict__ emb,
    const int* __restrict__ starts, const float* __restrict__ Wh,
    const float* __restrict__ bh, const float* __restrict__ Wo,
    const float* __restrict__ bo, const float* __restrict__ y,
    float* __restrict__ out, int Bval) {
    __shared__ float slds[4][HDIM];   // per-wave segment mean
    __shared__ float lred[4];

    int wave = threadIdx.x >> 6;
    int lane = threadIdx.x & 63;
    int s = blockIdx.x * 4 + wave;
    float lsum = 0.0f;

    if (s < Bval) {
        int t0 = starts[s];
        int t1 = starts[s + 1];
        int cnt = t1 - t0;
        int half = lane >> 5;   // which token of the pair
        int col  = lane & 31;   // float4 column within the 128-float row

        float4 acc = make_float4(0.f, 0.f, 0.f, 0.f);
        int i = t0 + half;      // this half-wave's token stream (stride 2)

        // prologue: prefetch first batch of token ids
        int tix[8];
        if (i + 14 < t1) {
            #pragma unroll
            for (int k = 0; k < 8; ++k) tix[k] = tok[i + 2 * k];
        }

        // main loop: 8 rows in flight per half-wave, tok ids one iter ahead
        while (i + 14 < t1) {
            float4 f[8];
            #pragma unroll
            for (int k = 0; k < 8; ++k)
                f[k] = ((const float4*)(emb + (size_t)tix[k] * HDIM))[col];

            int ni = i + 16;
            int ntix[8];
            if (ni + 14 < t1) {
                #pragma unroll
                for (int k = 0; k < 8; ++k) ntix[k] = tok[ni + 2 * k];
            }
            // force all 8 row loads issued before any accumulation
            __builtin_amdgcn_sched_barrier(0);
            #pragma unroll
            for (int k = 0; k < 8; ++k) {
                acc.x += f[k].x; acc.y += f[k].y;
                acc.z += f[k].z; acc.w += f[k].w;
            }
            #pragma unroll
            for (int k = 0; k < 8; ++k) tix[k] = ntix[k];
            i = ni;
        }

        // masked epilogue: one clamped 8-deep iteration covers the tail
        if (i < t1) {
            int lim = t1 - 1;
            int tix2[8]; float msk[8];
            #pragma unroll
            for (int k = 0; k < 8; ++k) {
                int ii = i + 2 * k;
                tix2[k] = tok[ii < lim ? ii : lim];
                msk[k] = (ii < t1) ? 1.0f : 0.0f;
            }
            float4 f[8];
            #pragma unroll
            for (int k = 0; k < 8; ++k)
                f[k] = ((const float4*)(emb + (size_t)tix2[k] * HDIM))[col];
            #pragma unroll
            for (int k = 0; k < 8; ++k) {
                acc.x = fmaf(f[k].x, msk[k], acc.x);
                acc.y = fmaf(f[k].y, msk[k], acc.y);
                acc.z = fmaf(f[k].z, msk[k], acc.z);
                acc.w = fmaf(f[k].w, msk[k], acc.w);
            }
        }

        // combine the two half-wave partial sums (lane l += lane l+32)
        acc.x += __shfl_down(acc.x, 32);
        acc.y += __shfl_down(acc.y, 32);
        acc.z += __shfl_down(acc.z, 32);
        acc.w += __shfl_down(acc.w, 32);

        if (half == 0) {
            float inv = 1.0f / (float)(cnt > 0 ? cnt : 1);
            acc.x *= inv; acc.y *= inv; acc.z *= inv; acc.w *= inv;
            ((float4*)&slds[wave][0])[col] = acc;
        }
        // same-wave LDS RAW below: compiler inserts the lgkmcnt wait.

        float2 bh2 = ((const float2*)bh)[lane];
        float2 wo2 = ((const float2*)Wo)[lane];
        // 2-way split accumulators (even/odd rows) halve the dependent chain
        float a0e = bh2.x, a1e = bh2.y, a0o = 0.0f, a1o = 0.0f;
        const float2* W2 = (const float2*)Wh;
        const float4* s4 = (const float4*)&slds[wave][0];
        #pragma unroll 4
        for (int q = 0; q < HDIM / 4; ++q) {
            float4 sv = s4[q];
            float2 w0 = W2[(4 * q + 0) * (HDIM / 2) + lane];
            float2 w1 = W2[(4 * q + 1) * (HDIM / 2) + lane];
            float2 w2 = W2[(4 * q + 2) * (HDIM / 2) + lane];
            float2 w3 = W2[(4 * q + 3) * (HDIM / 2) + lane];
            a0e = fmaf(sv.x, w0.x, a0e); a1e = fmaf(sv.x, w0.y, a1e);
            a0o = fmaf(sv.y, w1.x, a0o); a1o = fmaf(sv.y, w1.y, a1o);
            a0e = fmaf(sv.z, w2.x, a0e); a1e = fmaf(sv.z, w2.y, a1e);
            a0o = fmaf(sv.w, w3.x, a0o); a1o = fmaf(sv.w, w3.y, a1o);
        }
        float a0 = a0e + a0o, a1 = a1e + a1o;

        float pr = tanhf(a0) * wo2.x + tanhf(a1) * wo2.y;
        #pragma unroll
        for (int mm = 1; mm < 64; mm <<= 1) pr += __shfl_xor(pr, mm);

        if (lane == 0) {
            float z = pr + bo[0];
            float p = 1.0f / (1.0f + expf(-z));
            float lp  = fmaxf(logf(p),    -100.0f);
            float l1p = fmaxf(log1pf(-p), -100.0f);
            float yv = y[s];
            lsum = -(yv * lp + (1.0f - yv) * l1p);
        }
    }

    // whole waves take/skip the s<Bval branch; barrier is outside => legal
    if (lane == 0) lred[wave] = lsum;
    __syncthreads();
    if (threadIdx.x == 0)
        atomicAdd(out, lred[0] + lred[1] + lred[2] + lred[3]);
}

// ---------------------------------------------------------------------------
extern "C" void kernel_launch(void* const* d_in, const int* in_sizes, int n_in,
                              void* d_out, int out_size, void* d_ws, size_t ws_size,
                              hipStream_t stream) {
    const int*   tok = (const int*)d_in[0];
    const int*   seg = (const int*)d_in[1];
    const float* y   = (const float*)d_in[2];
    const float* emb = (const float*)d_in[3];
    const float* Wh  = (const float*)d_in[4];
    const float* bh  = (const float*)d_in[5];
    const float* Wo  = (const float*)d_in[6];
    const float* bo  = (const float*)d_in[7];

    int T_ = in_sizes[0];
    int B_ = in_sizes[2];

    float* out = (float*)d_out;
    int* starts = (int*)d_ws;   // only B+1 ints of workspace needed

    seg_bounds_kernel<<<(T_ + 255) / 256, 256, 0, stream>>>(seg, starts, T_, B_, out);
    fused_dan_kernel<<<(B_ + 3) / 4, 256, 0, stream>>>(tok, emb, starts, Wh, bh, Wo,
                                                       bo, y, out, B_);
}